// Round 2
// baseline (457.735 us; speedup 1.0000x reference)
//
#include <hip/hip_runtime.h>
#include <hip/hip_bf16.h>
#include <stdint.h>

// Problem constants (fixed by the reference)
#define N_EDGES   800000
#define N_NODESC  50000
#define HID       128

typedef __attribute__((ext_vector_type(8))) short bf16x8;  // 8 bf16 = 4 VGPRs (MFMA A/B frag)
typedef __attribute__((ext_vector_type(4))) float f32x4;   // MFMA C/D frag
typedef __attribute__((ext_vector_type(4))) unsigned int u32x4;

__device__ __forceinline__ short f2bf(float f) {
    union { float f; uint32_t u; } v; v.f = f;
    uint32_t r = v.u + 0x7FFFu + ((v.u >> 16) & 1u);   // round-to-nearest-even
    return (short)(r >> 16);
}

// pack two f32 -> bf16x2 (RNE) via native v_cvt_pk_bf16_f32 on gfx950
__device__ __forceinline__ uint32_t packbf2(float lo, float hi) {
    float2 t; t.x = lo; t.y = hi;
    __hip_bfloat162 h = __float22bfloat162_rn(t);
    uint32_t u;
    __builtin_memcpy(&u, &h, 4);       // __hip_bfloat162 not trivially copyable -> memcpy pun
    return u;
}

// packed bf16x2 (a+b) then relu:
//   __hadd2 -> native v_pk_add_bf16 (one RNE rounding);  relu via sign-mask, exact.
__device__ __forceinline__ uint32_t addrelu2(uint32_t a, uint32_t b) {
    __hip_bfloat162 ha, hb;
    __builtin_memcpy(&ha, &a, 4);
    __builtin_memcpy(&hb, &b, 4);
    __hip_bfloat162 s = __hadd2(ha, hb);
    uint32_t x;
    __builtin_memcpy(&x, &s, 4);
    uint32_t neg = (x & 0x80008000u) >> 15;      // 1 at bit0/bit16 where half negative
    return x & ~(neg * 0xFFFFu);                 // zero negative halves
}
__device__ __forceinline__ bf16x8 addrelu8(u32x4 p, u32x4 q) {
    u32x4 r;
    #pragma unroll
    for (int j = 0; j < 4; ++j) r[j] = addrelu2(p[j], q[j]);
    bf16x8 out;
    __builtin_memcpy(&out, &r, 16);
    return out;
}

// ---------------- workspace layout ----------------
// PQ  : bf16 [50000][1024]  (cols 0..511 = emb@W1_top + b1 "P'", 512..1023 = emb@W1_bot "Q")
// W1s : bf16 frag-major, 4*64 frags x 64 lanes x 8   (B-frags of W1cat [128,1024])
// W2s : bf16 frag-major, 16*8 frags x 64 lanes x 8   (B-frags of W2 [512,128])
// counts/cursor : int[50176]  histogram / running bin offsets  (padded to 196*256)
// bsum : int[256]             scan-block totals
// spk  : uint[800000]         col-sorted edges, packed (row<<16 | col)  [R1 fix: ONE
//                             4 B scattered write per edge instead of three — the 3x
//                             partial-line cross-XCD RMW was ~100 us of the R1 chain]
// pos  : int[800000]          sorted position of original edge e (written coalesced)
// tmp  : float[800000]        edge-kernel results in SORTED order (coalesced writes;
//                             R1's out[oe] scatter RMW'd 47 MB through HBM)
#define PQ_OFF    0UL
#define W1S_OFF   102400000UL                 // 50000*1024*2
#define W2S_OFF   (W1S_OFF + 262144UL)        // + 128*1024*2
#define CNT_OFF   (W2S_OFF + 131072UL)        // 102,793,216
#define BSUM_OFF  (CNT_OFF + 200704UL)
#define CUR_OFF   (BSUM_OFF + 1024UL)
#define SPK_OFF   (CUR_OFF + 200704UL)        // 103,195,648
#define POS_OFF   (SPK_OFF + 3200000UL)
#define TMP_OFF   (POS_OFF + 3200000UL)
// total ws: 112,795,648 bytes (same footprint as R1 — proven to fit)

#define SCAN_BLOCKS 196                       // ceil(50000/256); counts padded to 50176

// ============ kernel 0: weight convert + B-fragment swizzle ============
// B-frag for 16x16x32 bf16: lane l holds B[k = kc*32 + (l>>4)*8 + j][n = nt*16 + (l&15)], j=0..7
__global__ __launch_bounds__(256) void swizzle_kernel(const float* __restrict__ W1,
                                                      const float* __restrict__ W2,
                                                      short* __restrict__ W1s,
                                                      short* __restrict__ W2s) {
    int t = blockIdx.x * 256 + threadIdx.x;
    int lane = t & 63;
    int kq = lane >> 4;       // 0..3
    int nn = lane & 15;
    if (t < 16384) {          // W1cat: K=128, N=1024 -> kc 0..3, nt 0..63
        int frag = t >> 6;
        int kc = frag >> 6;
        int nt = frag & 63;
        int n = nt * 16 + nn;
        int kbase = kc * 32 + kq * 8;
        bf16x8 v;
        #pragma unroll
        for (int j = 0; j < 8; ++j) {
            int k = kbase + j;
            float f = (n < 512) ? W1[k * 512 + n] : W1[(128 + k) * 512 + (n - 512)];
            v[j] = f2bf(f);
        }
        *(bf16x8*)(W1s + frag * 512 + lane * 8) = v;
    } else if (t < 24576) {   // W2: K=512, N=128 -> kc 0..15, nt 0..7
        int t2 = t - 16384;
        int frag = t2 >> 6;
        int kc = frag >> 3;
        int nt = frag & 7;
        int n = nt * 16 + nn;
        int kbase = kc * 32 + kq * 8;
        bf16x8 v;
        #pragma unroll
        for (int j = 0; j < 8; ++j) v[j] = f2bf(W2[(kbase + j) * HID + n]);
        *(bf16x8*)(W2s + frag * 512 + lane * 8) = v;
    }
}

// ============ kernel 1: PQ = emb @ W1cat (+b1 on P half) ============
// grid 3125 x 256: block = 16 node rows, 4 waves each owning a 256-col slice.
__global__ __launch_bounds__(256) void precompute_kernel(const float* __restrict__ emb,
                                                         const short* __restrict__ W1s,
                                                         const float* __restrict__ b1,
                                                         short* __restrict__ PQ) {
    // per-wave tile: 16 rows x 256 cols bf16; row stride 272 shorts = 544 B
    __shared__ short tile[4][16][272];
    int lane = threadIdx.x & 63;
    int w = threadIdx.x >> 6;
    int nb = blockIdx.x * 16;
    int m = lane & 15;
    int kq = lane >> 4;

    const float* arow = emb + (size_t)(nb + m) * 128 + kq * 8;

    f32x4 acc[16];
    #pragma unroll
    for (int i = 0; i < 16; ++i) acc[i] = (f32x4){0.f, 0.f, 0.f, 0.f};

    #pragma unroll
    for (int kc = 0; kc < 4; ++kc) {
        f32x4 x0 = *(const f32x4*)(arow + kc * 32);
        f32x4 x1 = *(const f32x4*)(arow + kc * 32 + 4);
        u32x4 au;
        au[0] = packbf2(x0[0], x0[1]); au[1] = packbf2(x0[2], x0[3]);
        au[2] = packbf2(x1[0], x1[1]); au[3] = packbf2(x1[2], x1[3]);
        bf16x8 a;
        __builtin_memcpy(&a, &au, 16);
        #pragma unroll
        for (int nt = 0; nt < 16; ++nt) {
            int frag = kc * 64 + (w * 16 + nt);
            bf16x8 b = *(const bf16x8*)(W1s + frag * 512 + lane * 8);
            acc[nt] = __builtin_amdgcn_mfma_f32_16x16x32_bf16(a, b, acc[nt], 0, 0, 0);
        }
    }

    // C/D layout: col = lane&15, row = (lane>>4)*4 + r.  Fold b1 into the P half (n<512).
    #pragma unroll
    for (int nt = 0; nt < 16; ++nt) {
        int n = w * 256 + nt * 16 + m;
        float bias = (n < 512) ? b1[n] : 0.0f;
        #pragma unroll
        for (int r = 0; r < 4; ++r)
            tile[w][kq * 4 + r][nt * 16 + m] = f2bf(acc[nt][r] + bias);
    }

    // Read back row-major and store coalesced: 16 B per lane.
    #pragma unroll
    for (int s = 0; s < 8; ++s) {
        int row = s * 2 + (lane >> 5);
        int chunk = lane & 31;
        bf16x8 v = *(const bf16x8*)(&tile[w][row][chunk * 8]);
        *(bf16x8*)(PQ + (size_t)(nb + row) * 1024 + w * 256 + chunk * 8) = v;
    }
}

// ============ counting sort of edges by col ============
// Validated in R1: edge_kernel 316 -> 233 us (FETCH 731 -> 404 MB).  This round the
// chain itself is de-fatted: memset instead of zero_kernel, single packed 4 B scatter
// payload, pos[] written coalesced for the output permute.

__global__ __launch_bounds__(256) void hist_kernel(const int* __restrict__ ei,
                                                   int* __restrict__ counts) {
    int e = blockIdx.x * 256 + threadIdx.x;                // grid 3125
    atomicAdd(&counts[ei[e]], 1);
}

// per-256-bin exclusive scan; block totals to blocksum
__global__ __launch_bounds__(256) void scan1_kernel(const int* __restrict__ counts,
                                                    int* __restrict__ cursor,
                                                    int* __restrict__ blocksum) {
    __shared__ int sm[256];
    int t = threadIdx.x;
    int i = blockIdx.x * 256 + t;
    int v = counts[i];
    sm[t] = v;
    __syncthreads();
    #pragma unroll
    for (int off = 1; off < 256; off <<= 1) {
        int y = (t >= off) ? sm[t - off] : 0;
        __syncthreads();
        sm[t] += y;
        __syncthreads();
    }
    cursor[i] = sm[t] - v;                                 // exclusive within block
    if (t == 255) blocksum[blockIdx.x] = sm[t];
}

// exclusive scan of the 196 block sums (in place); tiny, LDS-serial
__global__ __launch_bounds__(256) void scan2_kernel(int* __restrict__ blocksum) {
    __shared__ int sm[256];
    int t = threadIdx.x;
    sm[t] = (t < SCAN_BLOCKS) ? blocksum[t] : 0;
    __syncthreads();
    if (t == 0) {
        int run = 0;
        for (int i = 0; i < SCAN_BLOCKS; ++i) { int c = sm[i]; sm[i] = run; run += c; }
    }
    __syncthreads();
    if (t < SCAN_BLOCKS) blocksum[t] = sm[t];
}

__global__ __launch_bounds__(256) void finalize_kernel(int* __restrict__ cursor,
                                                       const int* __restrict__ blockbase) {
    cursor[blockIdx.x * 256 + threadIdx.x] += blockbase[blockIdx.x];
}

__global__ __launch_bounds__(256) void scatter_kernel(const int* __restrict__ ei,
                                                      int* __restrict__ cursor,
                                                      unsigned int* __restrict__ spk,
                                                      int* __restrict__ pos) {
    int e = blockIdx.x * 256 + threadIdx.x;                // grid 3125
    int c = ei[e];
    int r = ei[N_EDGES + e];
    int p = atomicAdd(&cursor[c], 1);
    spk[p] = ((unsigned int)r << 16) | (unsigned int)c;    // 50000 < 2^16: both fit
    pos[e] = p;                                            // coalesced (e sequential)
}

// ============ kernel 2: per-edge fused layer1(gather+add+relu) + layer2(MFMA) + layer3 ============
// grid 3125 x 256: each wave owns 64 (col-sorted) edges as 4 m-tiles.
// 2 waves/SIMD (acc=128 AGPR + ~128 VGPR) -> deep VMEM software-pipelining via full unroll.
// launch_bounds(256,2): do NOT tighten — R4 showed (256,3) strangles prefetch depth.
// Results are written COALESCED in sorted order to tmp; permute_kernel restores order.
__global__ __launch_bounds__(256, 2) void edge_kernel(const short* __restrict__ PQ,
                                                      const unsigned int* __restrict__ spk,
                                                      const short* __restrict__ W2s,
                                                      const float* __restrict__ b2,
                                                      const float* __restrict__ W3,
                                                      const float* __restrict__ b3,
                                                      float* __restrict__ tmp) {
    int lane = threadIdx.x & 63;
    int w = threadIdx.x >> 6;
    int e0 = blockIdx.x * 256 + w * 64;
    int m = lane & 15;
    int kq = lane >> 4;

    unsigned int pk = spk[e0 + lane];          // 64 packed (row<<16|col), one 4 B load

    const short* pb[4];
    const short* qb[4];
    #pragma unroll
    for (int t = 0; t < 4; ++t) {
        unsigned int v = __shfl(pk, t * 16 + m, 64);
        int ce = (int)(v & 0xFFFFu);
        int re = (int)(v >> 16);
        pb[t] = PQ + (size_t)ce * 1024 + kq * 8;          // P' half (sorted: ~same line per tile)
        qb[t] = PQ + (size_t)re * 1024 + 512 + kq * 8;    // Q half (random, L3-resident)
    }

    f32x4 acc[4][8];
    #pragma unroll
    for (int t = 0; t < 4; ++t)
        #pragma unroll
        for (int nt = 0; nt < 8; ++nt) acc[t][nt] = (f32x4){0.f, 0.f, 0.f, 0.f};

    #pragma unroll
    for (int kc = 0; kc < 16; ++kc) {
        u32x4 p[4], q[4];
        #pragma unroll
        for (int t = 0; t < 4; ++t) {
            p[t] = *(const u32x4*)(pb[t] + kc * 32);
            q[t] = *(const u32x4*)(qb[t] + kc * 32);
        }
        bf16x8 b[8];
        #pragma unroll
        for (int nt = 0; nt < 8; ++nt)
            b[nt] = *(const bf16x8*)(W2s + (kc * 8 + nt) * 512 + lane * 8);
        #pragma unroll
        for (int t = 0; t < 4; ++t) {
            bf16x8 a = addrelu8(p[t], q[t]);
            #pragma unroll
            for (int nt = 0; nt < 8; ++nt)
                acc[t][nt] = __builtin_amdgcn_mfma_f32_16x16x32_bf16(a, b[nt], acc[t][nt], 0, 0, 0);
        }
    }

    // ---- epilogue: +b2, relu, dot with W3, +b3 (all f32); coalesced f32x4 store ----
    float b2v[8], w3v[8];
    #pragma unroll
    for (int nt = 0; nt < 8; ++nt) {
        b2v[nt] = b2[nt * 16 + m];
        w3v[nt] = W3[nt * 16 + m];
    }
    float b3s = b3[0];
    #pragma unroll
    for (int t = 0; t < 4; ++t) {
        float partial[4] = {0.f, 0.f, 0.f, 0.f};
        #pragma unroll
        for (int nt = 0; nt < 8; ++nt) {
            #pragma unroll
            for (int r = 0; r < 4; ++r) {
                float x2 = acc[t][nt][r] + b2v[nt];       // C row = kq*4+r, col = nt*16+m
                x2 = x2 > 0.f ? x2 : 0.f;
                partial[r] += x2 * w3v[nt];
            }
        }
        #pragma unroll
        for (int r = 0; r < 4; ++r) {
            #pragma unroll
            for (int off = 1; off < 16; off <<= 1)
                partial[r] += __shfl_xor(partial[r], off, 64);
        }
        if (m == 0) {                                     // lanes 0,16,32,48: contiguous 64 B
            f32x4 v;
            #pragma unroll
            for (int r = 0; r < 4; ++r) v[r] = partial[r] + b3s;
            *(f32x4*)(tmp + e0 + t * 16 + kq * 4) = v;
        }
    }
}

// ============ kernel 3: un-permute results to original edge order ============
// Coalesced read of pos + coalesced write of out; the only non-sequential access is a
// 4 B GATHER from the 3.2 MB tmp (L2/L3-resident) — gathers don't RMW-amplify.
__global__ __launch_bounds__(256) void permute_kernel(const float* __restrict__ tmp,
                                                      const int* __restrict__ pos,
                                                      float* __restrict__ out) {
    int e = blockIdx.x * 256 + threadIdx.x;                // grid 3125
    out[e] = tmp[pos[e]];
}

extern "C" void kernel_launch(void* const* d_in, const int* in_sizes, int n_in,
                              void* d_out, int out_size, void* d_ws, size_t ws_size,
                              hipStream_t stream) {
    const float* emb = (const float*)d_in[0];
    const int*   ei  = (const int*)d_in[1];
    const float* W1  = (const float*)d_in[2];
    const float* b1  = (const float*)d_in[3];
    const float* W2  = (const float*)d_in[4];
    const float* b2  = (const float*)d_in[5];
    const float* W3  = (const float*)d_in[6];
    const float* b3  = (const float*)d_in[7];
    float* out = (float*)d_out;

    short* PQ   = (short*)((char*)d_ws + PQ_OFF);
    short* W1s  = (short*)((char*)d_ws + W1S_OFF);
    short* W2s  = (short*)((char*)d_ws + W2S_OFF);
    int* counts = (int*)((char*)d_ws + CNT_OFF);
    int* bsum   = (int*)((char*)d_ws + BSUM_OFF);
    int* cursor = (int*)((char*)d_ws + CUR_OFF);
    unsigned int* spk = (unsigned int*)((char*)d_ws + SPK_OFF);
    int* pos    = (int*)((char*)d_ws + POS_OFF);
    float* tmp  = (float*)((char*)d_ws + TMP_OFF);

    swizzle_kernel<<<96, 256, 0, stream>>>(W1, W2, W1s, W2s);
    // edge counting-sort chain
    hipMemsetAsync(counts, 0, SCAN_BLOCKS * 256 * sizeof(int), stream);
    hist_kernel<<<N_EDGES / 256, 256, 0, stream>>>(ei, counts);
    scan1_kernel<<<SCAN_BLOCKS, 256, 0, stream>>>(counts, cursor, bsum);
    scan2_kernel<<<1, 256, 0, stream>>>(bsum);
    finalize_kernel<<<SCAN_BLOCKS, 256, 0, stream>>>(cursor, bsum);
    scatter_kernel<<<N_EDGES / 256, 256, 0, stream>>>(ei, cursor, spk, pos);

    precompute_kernel<<<N_NODESC / 16, 256, 0, stream>>>(emb, W1s, b1, PQ);            // 3125 blocks
    edge_kernel<<<N_EDGES / 256, 256, 0, stream>>>(PQ, spk, W2s, b2, W3, b3, tmp);     // 3125 blocks
    permute_kernel<<<N_EDGES / 256, 256, 0, stream>>>(tmp, pos, out);
}

// Round 3
// 455.595 us; speedup vs baseline: 1.0047x; 1.0047x over previous
//
#include <hip/hip_runtime.h>
#include <hip/hip_bf16.h>
#include <stdint.h>

// Problem constants (fixed by the reference)
#define N_EDGES   800000
#define N_NODESC  50000
#define HID       128

typedef __attribute__((ext_vector_type(8))) short bf16x8;  // 8 bf16 = 4 VGPRs (MFMA A/B frag)
typedef __attribute__((ext_vector_type(4))) float f32x4;   // MFMA C/D frag
typedef __attribute__((ext_vector_type(4))) unsigned int u32x4;

__device__ __forceinline__ short f2bf(float f) {
    union { float f; uint32_t u; } v; v.f = f;
    uint32_t r = v.u + 0x7FFFu + ((v.u >> 16) & 1u);   // round-to-nearest-even
    return (short)(r >> 16);
}

// pack two f32 -> bf16x2 (RNE) via native v_cvt_pk_bf16_f32 on gfx950
__device__ __forceinline__ uint32_t packbf2(float lo, float hi) {
    float2 t; t.x = lo; t.y = hi;
    __hip_bfloat162 h = __float22bfloat162_rn(t);
    uint32_t u;
    __builtin_memcpy(&u, &h, 4);       // __hip_bfloat162 not trivially copyable -> memcpy pun
    return u;
}

// packed bf16x2 (a+b) then relu:
//   __hadd2 -> native v_pk_add_bf16 (one RNE rounding);  relu via sign-mask, exact.
__device__ __forceinline__ uint32_t addrelu2(uint32_t a, uint32_t b) {
    __hip_bfloat162 ha, hb;
    __builtin_memcpy(&ha, &a, 4);
    __builtin_memcpy(&hb, &b, 4);
    __hip_bfloat162 s = __hadd2(ha, hb);
    uint32_t x;
    __builtin_memcpy(&x, &s, 4);
    uint32_t neg = (x & 0x80008000u) >> 15;      // 1 at bit0/bit16 where half negative
    return x & ~(neg * 0xFFFFu);                 // zero negative halves
}
__device__ __forceinline__ bf16x8 addrelu8(u32x4 p, u32x4 q) {
    u32x4 r;
    #pragma unroll
    for (int j = 0; j < 4; ++j) r[j] = addrelu2(p[j], q[j]);
    bf16x8 out;
    __builtin_memcpy(&out, &r, 16);
    return out;
}

// ---------------- workspace layout ----------------
// PQ  : bf16 [50000][1024]  (cols 0..511 = emb@W1_top + b1 "P'", 512..1023 = emb@W1_bot "Q")
// W1s : bf16 frag-major, 4*64 frags x 64 lanes x 8   (B-frags of W1cat [128,1024])
// W2s : bf16 frag-major, 16*8 frags x 64 lanes x 8   (B-frags of W2 [512,128])
// counts/cursor : int[50176]  histogram / running bin offsets  (padded to 196*256)
// bsum : int[256]             scan-block totals
// spk  : uint[800000]         col-sorted edges, packed (row<<16 | col)
// pos  : int[800000]          sorted position of original edge e (written coalesced)
// tmp  : float[800000]        edge-kernel results in SORTED order (coalesced writes)
#define PQ_OFF    0UL
#define W1S_OFF   102400000UL                 // 50000*1024*2
#define W2S_OFF   (W1S_OFF + 262144UL)        // + 128*1024*2
#define CNT_OFF   (W2S_OFF + 131072UL)        // 102,793,216
#define BSUM_OFF  (CNT_OFF + 200704UL)
#define CUR_OFF   (BSUM_OFF + 1024UL)
#define SPK_OFF   (CUR_OFF + 200704UL)        // 103,195,648
#define POS_OFF   (SPK_OFF + 3200000UL)
#define TMP_OFF   (POS_OFF + 3200000UL)
// total ws: 112,795,648 bytes (proven to fit in R1/R2)

#define SCAN_BLOCKS 196                       // ceil(50000/256); counts padded to 50176

// ============ kernel 0: weight convert + B-fragment swizzle ============
// B-frag for 16x16x32 bf16: lane l holds B[k = kc*32 + (l>>4)*8 + j][n = nt*16 + (l&15)], j=0..7
__global__ __launch_bounds__(256) void swizzle_kernel(const float* __restrict__ W1,
                                                      const float* __restrict__ W2,
                                                      short* __restrict__ W1s,
                                                      short* __restrict__ W2s) {
    int t = blockIdx.x * 256 + threadIdx.x;
    int lane = t & 63;
    int kq = lane >> 4;       // 0..3
    int nn = lane & 15;
    if (t < 16384) {          // W1cat: K=128, N=1024 -> kc 0..3, nt 0..63
        int frag = t >> 6;
        int kc = frag >> 6;
        int nt = frag & 63;
        int n = nt * 16 + nn;
        int kbase = kc * 32 + kq * 8;
        bf16x8 v;
        #pragma unroll
        for (int j = 0; j < 8; ++j) {
            int k = kbase + j;
            float f = (n < 512) ? W1[k * 512 + n] : W1[(128 + k) * 512 + (n - 512)];
            v[j] = f2bf(f);
        }
        *(bf16x8*)(W1s + frag * 512 + lane * 8) = v;
    } else if (t < 24576) {   // W2: K=512, N=128 -> kc 0..15, nt 0..7
        int t2 = t - 16384;
        int frag = t2 >> 6;
        int kc = frag >> 3;
        int nt = frag & 7;
        int n = nt * 16 + nn;
        int kbase = kc * 32 + kq * 8;
        bf16x8 v;
        #pragma unroll
        for (int j = 0; j < 8; ++j) v[j] = f2bf(W2[(kbase + j) * HID + n]);
        *(bf16x8*)(W2s + frag * 512 + lane * 8) = v;
    }
}

// ============ kernel 1: PQ = emb @ W1cat (+b1 on P half) ============
// grid 3125 x 256: block = 16 node rows, 4 waves each owning a 256-col slice.
__global__ __launch_bounds__(256) void precompute_kernel(const float* __restrict__ emb,
                                                         const short* __restrict__ W1s,
                                                         const float* __restrict__ b1,
                                                         short* __restrict__ PQ) {
    // per-wave tile: 16 rows x 256 cols bf16; row stride 272 shorts = 544 B
    __shared__ short tile[4][16][272];
    int lane = threadIdx.x & 63;
    int w = threadIdx.x >> 6;
    int nb = blockIdx.x * 16;
    int m = lane & 15;
    int kq = lane >> 4;

    const float* arow = emb + (size_t)(nb + m) * 128 + kq * 8;

    f32x4 acc[16];
    #pragma unroll
    for (int i = 0; i < 16; ++i) acc[i] = (f32x4){0.f, 0.f, 0.f, 0.f};

    #pragma unroll
    for (int kc = 0; kc < 4; ++kc) {
        f32x4 x0 = *(const f32x4*)(arow + kc * 32);
        f32x4 x1 = *(const f32x4*)(arow + kc * 32 + 4);
        u32x4 au;
        au[0] = packbf2(x0[0], x0[1]); au[1] = packbf2(x0[2], x0[3]);
        au[2] = packbf2(x1[0], x1[1]); au[3] = packbf2(x1[2], x1[3]);
        bf16x8 a;
        __builtin_memcpy(&a, &au, 16);
        #pragma unroll
        for (int nt = 0; nt < 16; ++nt) {
            int frag = kc * 64 + (w * 16 + nt);
            bf16x8 b = *(const bf16x8*)(W1s + frag * 512 + lane * 8);
            acc[nt] = __builtin_amdgcn_mfma_f32_16x16x32_bf16(a, b, acc[nt], 0, 0, 0);
        }
    }

    // C/D layout: col = lane&15, row = (lane>>4)*4 + r.  Fold b1 into the P half (n<512).
    #pragma unroll
    for (int nt = 0; nt < 16; ++nt) {
        int n = w * 256 + nt * 16 + m;
        float bias = (n < 512) ? b1[n] : 0.0f;
        #pragma unroll
        for (int r = 0; r < 4; ++r)
            tile[w][kq * 4 + r][nt * 16 + m] = f2bf(acc[nt][r] + bias);
    }

    // Read back row-major and store coalesced: 16 B per lane.
    #pragma unroll
    for (int s = 0; s < 8; ++s) {
        int row = s * 2 + (lane >> 5);
        int chunk = lane & 31;
        bf16x8 v = *(const bf16x8*)(&tile[w][row][chunk * 8]);
        *(bf16x8*)(PQ + (size_t)(nb + row) * 1024 + w * 256 + chunk * 8) = v;
    }
}

// ============ counting sort of edges by col ============
// Validated R1/R2: edge FETCH 731 -> ~395 MB (P-side gathers become L2 hits).

__global__ __launch_bounds__(256) void hist_kernel(const int* __restrict__ ei,
                                                   int* __restrict__ counts) {
    int e = blockIdx.x * 256 + threadIdx.x;                // grid 3125
    atomicAdd(&counts[ei[e]], 1);
}

// per-256-bin exclusive scan; block totals to blocksum
__global__ __launch_bounds__(256) void scan1_kernel(const int* __restrict__ counts,
                                                    int* __restrict__ cursor,
                                                    int* __restrict__ blocksum) {
    __shared__ int sm[256];
    int t = threadIdx.x;
    int i = blockIdx.x * 256 + t;
    int v = counts[i];
    sm[t] = v;
    __syncthreads();
    #pragma unroll
    for (int off = 1; off < 256; off <<= 1) {
        int y = (t >= off) ? sm[t - off] : 0;
        __syncthreads();
        sm[t] += y;
        __syncthreads();
    }
    cursor[i] = sm[t] - v;                                 // exclusive within block
    if (t == 255) blocksum[blockIdx.x] = sm[t];
}

// fused scan2+finalize: each block redundantly computes its exclusive base over
// the 196 block sums (one 256-wide reduce) and adds it to its cursor slice.
__global__ __launch_bounds__(256) void finalize2_kernel(int* __restrict__ cursor,
                                                        const int* __restrict__ bsum) {
    __shared__ int wsum[4];
    int t = threadIdx.x;
    int b = blockIdx.x;
    int v = (t < b && t < SCAN_BLOCKS) ? bsum[t] : 0;      // exclusive: j < b
    #pragma unroll
    for (int off = 1; off < 64; off <<= 1) v += __shfl_xor(v, off, 64);
    if ((t & 63) == 0) wsum[t >> 6] = v;
    __syncthreads();
    int base = wsum[0] + wsum[1] + wsum[2] + wsum[3];
    cursor[b * 256 + t] += base;
}

__global__ __launch_bounds__(256) void scatter_kernel(const int* __restrict__ ei,
                                                      int* __restrict__ cursor,
                                                      unsigned int* __restrict__ spk,
                                                      int* __restrict__ pos) {
    int e = blockIdx.x * 256 + threadIdx.x;                // grid 3125
    int c = ei[e];
    int r = ei[N_EDGES + e];
    int p = atomicAdd(&cursor[c], 1);
    spk[p] = ((unsigned int)r << 16) | (unsigned int)c;    // 50000 < 2^16: both fit
    pos[e] = p;                                            // coalesced (e sequential)
}

// ============ kernel 2: per-edge fused layer1(gather+add+relu) + layer2(MFMA) + layer3 ============
// R3 restructure: 2 m-tiles per wave (32 edges), grid 6250.
// Rationale: R0-R2 all ran 2 waves/SIMD (128 VGPR + 128 AGPR = full 256-reg budget) with
// ~50% stall on random L3 reads.  Halving the accumulator (64 AGPR) + halving staging
// state fits under 512/3 = 170 regs -> 3 waves/SIMD = +50% memory-level parallelism at
// IDENTICAL locality (m-tile is still 16 consecutive col-sorted edges).  Prior "(256,3)
// hurt" was with the 4-tile body forced under the cap (starvation); 2 tiles fit natively.
__global__ __launch_bounds__(256, 3) void edge_kernel(const short* __restrict__ PQ,
                                                      const unsigned int* __restrict__ spk,
                                                      const short* __restrict__ W2s,
                                                      const float* __restrict__ b2,
                                                      const float* __restrict__ W3,
                                                      const float* __restrict__ b3,
                                                      float* __restrict__ tmp) {
    int lane = threadIdx.x & 63;
    int w = threadIdx.x >> 6;
    int e0 = blockIdx.x * 128 + w * 32;
    int m = lane & 15;
    int kq = lane >> 4;

    unsigned int pk = spk[e0 + (lane & 31)];   // 32 packed (row<<16|col), 2-way dup load

    const short* pb[2];
    const short* qb[2];
    #pragma unroll
    for (int t = 0; t < 2; ++t) {
        unsigned int v = __shfl(pk, t * 16 + m, 64);
        int ce = (int)(v & 0xFFFFu);
        int re = (int)(v >> 16);
        pb[t] = PQ + (size_t)ce * 1024 + kq * 8;          // P' half (sorted: ~same line per tile)
        qb[t] = PQ + (size_t)re * 1024 + 512 + kq * 8;    // Q half (random, L3-resident)
    }

    f32x4 acc[2][8];
    #pragma unroll
    for (int t = 0; t < 2; ++t)
        #pragma unroll
        for (int nt = 0; nt < 8; ++nt) acc[t][nt] = (f32x4){0.f, 0.f, 0.f, 0.f};

    #pragma unroll
    for (int kc = 0; kc < 16; ++kc) {
        u32x4 p[2], q[2];
        #pragma unroll
        for (int t = 0; t < 2; ++t) {
            p[t] = *(const u32x4*)(pb[t] + kc * 32);
            q[t] = *(const u32x4*)(qb[t] + kc * 32);
        }
        bf16x8 b[8];
        #pragma unroll
        for (int nt = 0; nt < 8; ++nt)
            b[nt] = *(const bf16x8*)(W2s + (kc * 8 + nt) * 512 + lane * 8);
        #pragma unroll
        for (int t = 0; t < 2; ++t) {
            bf16x8 a = addrelu8(p[t], q[t]);
            #pragma unroll
            for (int nt = 0; nt < 8; ++nt)
                acc[t][nt] = __builtin_amdgcn_mfma_f32_16x16x32_bf16(a, b[nt], acc[t][nt], 0, 0, 0);
        }
    }

    // ---- epilogue: +b2, relu, dot with W3, +b3 (all f32); coalesced f32x4 store ----
    float b2v[8], w3v[8];
    #pragma unroll
    for (int nt = 0; nt < 8; ++nt) {
        b2v[nt] = b2[nt * 16 + m];
        w3v[nt] = W3[nt * 16 + m];
    }
    float b3s = b3[0];
    #pragma unroll
    for (int t = 0; t < 2; ++t) {
        float partial[4] = {0.f, 0.f, 0.f, 0.f};
        #pragma unroll
        for (int nt = 0; nt < 8; ++nt) {
            #pragma unroll
            for (int r = 0; r < 4; ++r) {
                float x2 = acc[t][nt][r] + b2v[nt];       // C row = kq*4+r, col = nt*16+m
                x2 = x2 > 0.f ? x2 : 0.f;
                partial[r] += x2 * w3v[nt];
            }
        }
        #pragma unroll
        for (int r = 0; r < 4; ++r) {
            #pragma unroll
            for (int off = 1; off < 16; off <<= 1)
                partial[r] += __shfl_xor(partial[r], off, 64);
        }
        if (m == 0) {                                     // lanes 0,16,32,48: contiguous 64 B
            f32x4 v;
            #pragma unroll
            for (int r = 0; r < 4; ++r) v[r] = partial[r] + b3s;
            *(f32x4*)(tmp + e0 + t * 16 + kq * 4) = v;
        }
    }
}

// ============ kernel 3: un-permute results to original edge order ============
__global__ __launch_bounds__(256) void permute_kernel(const float* __restrict__ tmp,
                                                      const int* __restrict__ pos,
                                                      float* __restrict__ out) {
    int e = blockIdx.x * 256 + threadIdx.x;                // grid 3125
    out[e] = tmp[pos[e]];
}

extern "C" void kernel_launch(void* const* d_in, const int* in_sizes, int n_in,
                              void* d_out, int out_size, void* d_ws, size_t ws_size,
                              hipStream_t stream) {
    const float* emb = (const float*)d_in[0];
    const int*   ei  = (const int*)d_in[1];
    const float* W1  = (const float*)d_in[2];
    const float* b1  = (const float*)d_in[3];
    const float* W2  = (const float*)d_in[4];
    const float* b2  = (const float*)d_in[5];
    const float* W3  = (const float*)d_in[6];
    const float* b3  = (const float*)d_in[7];
    float* out = (float*)d_out;

    short* PQ   = (short*)((char*)d_ws + PQ_OFF);
    short* W1s  = (short*)((char*)d_ws + W1S_OFF);
    short* W2s  = (short*)((char*)d_ws + W2S_OFF);
    int* counts = (int*)((char*)d_ws + CNT_OFF);
    int* bsum   = (int*)((char*)d_ws + BSUM_OFF);
    int* cursor = (int*)((char*)d_ws + CUR_OFF);
    unsigned int* spk = (unsigned int*)((char*)d_ws + SPK_OFF);
    int* pos    = (int*)((char*)d_ws + POS_OFF);
    float* tmp  = (float*)((char*)d_ws + TMP_OFF);

    swizzle_kernel<<<96, 256, 0, stream>>>(W1, W2, W1s, W2s);
    // edge counting-sort chain
    hipMemsetAsync(counts, 0, SCAN_BLOCKS * 256 * sizeof(int), stream);
    hist_kernel<<<N_EDGES / 256, 256, 0, stream>>>(ei, counts);
    scan1_kernel<<<SCAN_BLOCKS, 256, 0, stream>>>(counts, cursor, bsum);
    finalize2_kernel<<<SCAN_BLOCKS, 256, 0, stream>>>(cursor, bsum);
    scatter_kernel<<<N_EDGES / 256, 256, 0, stream>>>(ei, cursor, spk, pos);

    precompute_kernel<<<N_NODESC / 16, 256, 0, stream>>>(emb, W1s, b1, PQ);            // 3125 blocks
    edge_kernel<<<N_EDGES / 128, 256, 0, stream>>>(PQ, spk, W2s, b2, W3, b3, tmp);     // 6250 blocks
    permute_kernel<<<N_EDGES / 256, 256, 0, stream>>>(tmp, pos, out);
}